// Round 8
// baseline (241.332 us; speedup 1.0000x reference)
//
#include <hip/hip_runtime.h>
#include <hip/hip_bf16.h>
#include <math.h>

namespace {

constexpr int B_ = 8, L_ = 4096, C_ = 128, K_ = 7;
constexpr int LP = L_ - K_ + 1;        // 4090
constexpr int CK = C_ * K_;            // 896

typedef __attribute__((ext_vector_type(8))) short short8v;
typedef __attribute__((ext_vector_type(4))) float f32x4;

__device__ __forceinline__ unsigned short bf16_rne(float f) {
    __hip_bfloat16 h = __float2bfloat16(f);
    return *reinterpret_cast<unsigned short*>(&h);
}

__device__ __forceinline__ float fast_tanh(float v) {
    float a = fabsf(v);
    float e = __expf(2.0f * a);
    float t = 1.0f - 2.0f / (e + 1.0f);   // large a -> e=inf -> t=1
    return v < 0.0f ? -t : t;
}

// split fp32 -> (hi = truncated bf16, lo = RNE bf16 of exact residual)
__device__ __forceinline__ void split1(float f, short& h, short& l) {
    unsigned u = __float_as_uint(f);
    h = (short)(u >> 16);
    float hf = __uint_as_float(u & 0xFFFF0000u);
    l = (short)bf16_rne(f - hf);
}

// one fused kernel: 256 l-rows x 16 d per block; 4 waves x 64 rows each.
// m-tiles processed in PAIRS (outer loop, not unrolled) to keep the live
// register set ~150 VGPR — the round-7 version held all 4 m-tiles live and
// spilled to scratch (VGPR capped at 128, WRITE_SIZE 82MB vs 17MB output).
__global__ __launch_bounds__(256, 2) void sidechain_fused(
        const float* __restrict__ x, const float* __restrict__ W,
        float* __restrict__ out) {
    __shared__ unsigned short BsHi[7 * 16 * C_];   // [k][d_local][cin], XOR-swizzled granules
    __shared__ unsigned short BsLo[7 * 16 * C_];

    const int tid = threadIdx.x;
    const int b  = blockIdx.x >> 4;
    const int l0 = (blockIdx.x & 15) * 256;
    const int d0 = blockIdx.y * 16;

    const float* xb = x + (size_t)b * (L_ * C_);

    // ---- stage + convert W tile straight from fp32 global
    {
        const int dl = tid >> 4;       // 0..15: d row
        const int g  = tid & 15;       // cin granule (8 cins)
        const int gp = g ^ dl;         // swizzled granule slot
        const float* wp = W + (size_t)(d0 + dl) * CK + g * 56;  // 8 cins x 7 k, contiguous
        float wbuf[56];
#pragma unroll
        for (int i = 0; i < 14; ++i)
            *reinterpret_cast<float4*>(&wbuf[i * 4]) =
                *reinterpret_cast<const float4*>(&wp[i * 4]);
#pragma unroll
        for (int k = 0; k < 7; ++k) {
            short8v h, l;
#pragma unroll
            for (int c = 0; c < 8; ++c) {
                short hh, ll;
                split1(wbuf[c * 7 + k], hh, ll);
                h[c] = hh; l[c] = ll;
            }
            *reinterpret_cast<short8v*>(&BsHi[(k * 16 + dl) * C_ + gp * 8]) = h;
            *reinterpret_cast<short8v*>(&BsLo[(k * 16 + dl) * C_ + gp * 8]) = l;
        }
    }
    __syncthreads();

    const int wv   = tid >> 6;
    const int lane = tid & 63;
    const int rA   = lane & 15;    // A row / B col(d) / D col
    const int kg   = lane >> 4;    // 0..3
    const int dcol = d0 + rA;

#pragma unroll 1
    for (int half = 0; half < 2; ++half) {     // 2 m-tiles per iteration
        // ---- A fragments for this pair: load fp32, split in-register
        short8v Ahi[2][4], Alo[2][4];
#pragma unroll
        for (int m = 0; m < 2; ++m) {
            int mt = half * 2 + m;
            int r = l0 + 6 + wv * 64 + mt * 16 + rA;
            if (r > L_ - 1) r = L_ - 1;        // clamped rows feed masked-out outputs only
            const float* xr = xb + (size_t)r * C_;
#pragma unroll
            for (int ks = 0; ks < 4; ++ks) {
                const float* p = xr + ks * 32 + kg * 8;
                const float4 f0 = *reinterpret_cast<const float4*>(p);
                const float4 f1 = *reinterpret_cast<const float4*>(p + 4);
                const float f[8] = {f0.x, f0.y, f0.z, f0.w, f1.x, f1.y, f1.z, f1.w};
                short8v h, l;
#pragma unroll
                for (int c = 0; c < 8; ++c) {
                    short hh, ll;
                    split1(f[c], hh, ll);
                    h[c] = hh; l[c] = ll;
                }
                Ahi[m][ks] = h; Alo[m][ks] = l;
            }
        }

        // ---- epilogue x values for this pair: 10 rows cover r(0..3)+nt(0..6)
        float xv[2][10];
#pragma unroll
        for (int m = 0; m < 2; ++m) {
            int mt = half * 2 + m;
            int base = l0 + wv * 64 + mt * 16 + kg * 4;
#pragma unroll
            for (int r2 = 0; r2 < 10; ++r2) {
                int row = base + r2;
                if (row > L_ - 1) row = L_ - 1;    // OOB only for masked-out outputs
                xv[m][r2] = xb[(size_t)row * C_ + dcol];
            }
        }

        f32x4 oacc[2];
#pragma unroll
        for (int m = 0; m < 2; ++m) oacc[m] = (f32x4)(0.0f);

#pragma unroll
        for (int nt = 0; nt < 7; ++nt) {       // n-tile == tap k
            f32x4 aHH[2], aHL[2], aLH[2];      // 6 independent MFMA chains
#pragma unroll
            for (int m = 0; m < 2; ++m) {
                aHH[m] = (f32x4)(0.0f); aHL[m] = (f32x4)(0.0f); aLH[m] = (f32x4)(0.0f);
            }
#pragma unroll
            for (int ks = 0; ks < 4; ++ks) {
                int gp = (ks * 4 + kg) ^ rA;
                const short8v Bh = *reinterpret_cast<const short8v*>(&BsHi[(nt * 16 + rA) * C_ + gp * 8]);
                const short8v Bl = *reinterpret_cast<const short8v*>(&BsLo[(nt * 16 + rA) * C_ + gp * 8]);
#pragma unroll
                for (int m = 0; m < 2; ++m) {
                    aHH[m] = __builtin_amdgcn_mfma_f32_16x16x32_bf16(Ahi[m][ks], Bh, aHH[m], 0, 0, 0);
                    aHL[m] = __builtin_amdgcn_mfma_f32_16x16x32_bf16(Ahi[m][ks], Bl, aHL[m], 0, 0, 0);
                    aLH[m] = __builtin_amdgcn_mfma_f32_16x16x32_bf16(Alo[m][ks], Bh, aLH[m], 0, 0, 0);
                }
            }
            // fused FIR epilogue for tap nt (register-resident x)
#pragma unroll
            for (int m = 0; m < 2; ++m)
#pragma unroll
                for (int r = 0; r < 4; ++r) {
                    float s = aHH[m][r] + aHL[m][r] + aLH[m][r];
                    oacc[m][r] = fmaf(xv[m][r + nt], fast_tanh(s), oacc[m][r]);
                }
        }

#pragma unroll
        for (int m = 0; m < 2; ++m) {
            int mt = half * 2 + m;
#pragma unroll
            for (int r = 0; r < 4; ++r) {
                int l = l0 + wv * 64 + mt * 16 + kg * 4 + r;
                if (l < LP) out[((size_t)b * LP + l) * C_ + dcol] = oacc[m][r];
            }
        }
    }
}

} // namespace

extern "C" void kernel_launch(void* const* d_in, const int* in_sizes, int n_in,
                              void* d_out, int out_size, void* d_ws, size_t ws_size,
                              hipStream_t stream) {
    const float* x = (const float*)d_in[0];
    const float* w = (const float*)d_in[1];
    float* out     = (float*)d_out;
    (void)d_ws; (void)ws_size; (void)in_sizes; (void)n_in; (void)out_size;

    dim3 grid(B_ * 16, C_ / 16);
    sidechain_fused<<<grid, dim3(256), 0, stream>>>(x, w, out);
}

// Round 9
// 147.873 us; speedup vs baseline: 1.6320x; 1.6320x over previous
//
#include <hip/hip_runtime.h>
#include <hip/hip_bf16.h>
#include <math.h>

namespace {

constexpr int B_ = 8, L_ = 4096, C_ = 128, K_ = 7;
constexpr int LP = L_ - K_ + 1;        // 4090
constexpr int CK = C_ * K_;            // 896

typedef __attribute__((ext_vector_type(8))) short short8v;
typedef __attribute__((ext_vector_type(4))) float f32x4;

__device__ __forceinline__ unsigned short bf16_rne(float f) {
    __hip_bfloat16 h = __float2bfloat16(f);
    return *reinterpret_cast<unsigned short*>(&h);
}

__device__ __forceinline__ float fast_tanh(float v) {
    float a = fabsf(v);
    float e = __expf(2.0f * a);
    float t = 1.0f - 2.0f / (e + 1.0f);   // large a -> e=inf -> t=1
    return v < 0.0f ? -t : t;
}

// split fp32 -> (hi = truncated bf16, lo = RNE bf16 of exact residual)
__device__ __forceinline__ void split1(float f, short& h, short& l) {
    unsigned u = __float_as_uint(f);
    h = (short)(u >> 16);
    float hf = __uint_as_float(u & 0xFFFF0000u);
    l = (short)bf16_rne(f - hf);
}

// one fused kernel: 256 l-rows x 16 d per block; 4 waves x 64 rows each.
// m-tiles in PAIRS (outer loop) for a ~150-VGPR live set.
// __launch_bounds__(256, 1): rounds 7/8 used (256,2), which empirically pins
// the allocator at 128 VGPR -> massive scratch spills (WRITE_SIZE 353MB vs
// 17MB of real output). LDS (57KB) already limits us to 2 blocks/CU = 2
// waves/SIMD, i.e. a 256-VGPR budget — so allowing the allocator up to that
// costs no occupancy and removes the spills.
__global__ __launch_bounds__(256, 1) void sidechain_fused(
        const float* __restrict__ x, const float* __restrict__ W,
        float* __restrict__ out) {
    __shared__ unsigned short BsHi[7 * 16 * C_];   // [k][d_local][cin], XOR-swizzled granules
    __shared__ unsigned short BsLo[7 * 16 * C_];

    const int tid = threadIdx.x;
    const int b  = blockIdx.x >> 4;
    const int l0 = (blockIdx.x & 15) * 256;
    const int d0 = blockIdx.y * 16;

    const float* xb = x + (size_t)b * (L_ * C_);

    // ---- stage + convert W tile straight from fp32 global
    {
        const int dl = tid >> 4;       // 0..15: d row
        const int g  = tid & 15;       // cin granule (8 cins)
        const int gp = g ^ dl;         // swizzled granule slot
        const float* wp = W + (size_t)(d0 + dl) * CK + g * 56;  // 8 cins x 7 k, contiguous
        float wbuf[56];
#pragma unroll
        for (int i = 0; i < 14; ++i)
            *reinterpret_cast<float4*>(&wbuf[i * 4]) =
                *reinterpret_cast<const float4*>(&wp[i * 4]);
#pragma unroll
        for (int k = 0; k < 7; ++k) {
            short8v h, l;
#pragma unroll
            for (int c = 0; c < 8; ++c) {
                short hh, ll;
                split1(wbuf[c * 7 + k], hh, ll);
                h[c] = hh; l[c] = ll;
            }
            *reinterpret_cast<short8v*>(&BsHi[(k * 16 + dl) * C_ + gp * 8]) = h;
            *reinterpret_cast<short8v*>(&BsLo[(k * 16 + dl) * C_ + gp * 8]) = l;
        }
    }
    __syncthreads();

    const int wv   = tid >> 6;
    const int lane = tid & 63;
    const int rA   = lane & 15;    // A row / B col(d) / D col
    const int kg   = lane >> 4;    // 0..3
    const int dcol = d0 + rA;

#pragma unroll 1
    for (int half = 0; half < 2; ++half) {     // 2 m-tiles per iteration
        // ---- A fragments for this pair: load fp32, split in-register
        short8v Ahi[2][4], Alo[2][4];
#pragma unroll
        for (int m = 0; m < 2; ++m) {
            int mt = half * 2 + m;
            int r = l0 + 6 + wv * 64 + mt * 16 + rA;
            if (r > L_ - 1) r = L_ - 1;        // clamped rows feed masked-out outputs only
            const float* xr = xb + (size_t)r * C_;
#pragma unroll
            for (int ks = 0; ks < 4; ++ks) {
                const float* p = xr + ks * 32 + kg * 8;
                const float4 f0 = *reinterpret_cast<const float4*>(p);
                const float4 f1 = *reinterpret_cast<const float4*>(p + 4);
                const float f[8] = {f0.x, f0.y, f0.z, f0.w, f1.x, f1.y, f1.z, f1.w};
                short8v h, l;
#pragma unroll
                for (int c = 0; c < 8; ++c) {
                    short hh, ll;
                    split1(f[c], hh, ll);
                    h[c] = hh; l[c] = ll;
                }
                Ahi[m][ks] = h; Alo[m][ks] = l;
            }
        }

        // ---- epilogue x values for this pair: 10 rows cover r(0..3)+nt(0..6)
        float xv[2][10];
#pragma unroll
        for (int m = 0; m < 2; ++m) {
            int mt = half * 2 + m;
            int base = l0 + wv * 64 + mt * 16 + kg * 4;
#pragma unroll
            for (int r2 = 0; r2 < 10; ++r2) {
                int row = base + r2;
                if (row > L_ - 1) row = L_ - 1;    // OOB only for masked-out outputs
                xv[m][r2] = xb[(size_t)row * C_ + dcol];
            }
        }

        f32x4 oacc[2];
#pragma unroll
        for (int m = 0; m < 2; ++m) oacc[m] = (f32x4)(0.0f);

#pragma unroll
        for (int nt = 0; nt < 7; ++nt) {       // n-tile == tap k
            f32x4 aHH[2], aHL[2], aLH[2];      // 6 independent MFMA chains
#pragma unroll
            for (int m = 0; m < 2; ++m) {
                aHH[m] = (f32x4)(0.0f); aHL[m] = (f32x4)(0.0f); aLH[m] = (f32x4)(0.0f);
            }
#pragma unroll
            for (int ks = 0; ks < 4; ++ks) {
                int gp = (ks * 4 + kg) ^ rA;
                const short8v Bh = *reinterpret_cast<const short8v*>(&BsHi[(nt * 16 + rA) * C_ + gp * 8]);
                const short8v Bl = *reinterpret_cast<const short8v*>(&BsLo[(nt * 16 + rA) * C_ + gp * 8]);
#pragma unroll
                for (int m = 0; m < 2; ++m) {
                    aHH[m] = __builtin_amdgcn_mfma_f32_16x16x32_bf16(Ahi[m][ks], Bh, aHH[m], 0, 0, 0);
                    aHL[m] = __builtin_amdgcn_mfma_f32_16x16x32_bf16(Ahi[m][ks], Bl, aHL[m], 0, 0, 0);
                    aLH[m] = __builtin_amdgcn_mfma_f32_16x16x32_bf16(Alo[m][ks], Bh, aLH[m], 0, 0, 0);
                }
            }
            // fused FIR epilogue for tap nt (register-resident x)
#pragma unroll
            for (int m = 0; m < 2; ++m)
#pragma unroll
                for (int r = 0; r < 4; ++r) {
                    float s = aHH[m][r] + aHL[m][r] + aLH[m][r];
                    oacc[m][r] = fmaf(xv[m][r + nt], fast_tanh(s), oacc[m][r]);
                }
        }

#pragma unroll
        for (int m = 0; m < 2; ++m) {
            int mt = half * 2 + m;
#pragma unroll
            for (int r = 0; r < 4; ++r) {
                int l = l0 + wv * 64 + mt * 16 + kg * 4 + r;
                if (l < LP) out[((size_t)b * LP + l) * C_ + dcol] = oacc[m][r];
            }
        }
    }
}

} // namespace

extern "C" void kernel_launch(void* const* d_in, const int* in_sizes, int n_in,
                              void* d_out, int out_size, void* d_ws, size_t ws_size,
                              hipStream_t stream) {
    const float* x = (const float*)d_in[0];
    const float* w = (const float*)d_in[1];
    float* out     = (float*)d_out;
    (void)d_ws; (void)ws_size; (void)in_sizes; (void)n_in; (void)out_size;

    dim3 grid(B_ * 16, C_ / 16);
    sidechain_fused<<<grid, dim3(256), 0, stream>>>(x, w, out);
}

// Round 11
// 90.878 us; speedup vs baseline: 2.6556x; 1.6272x over previous
//
#include <hip/hip_runtime.h>
#include <hip/hip_bf16.h>
#include <math.h>

namespace {

constexpr int B_ = 8, L_ = 4096, C_ = 128, K_ = 7;
constexpr int LP = L_ - K_ + 1;        // 4090
constexpr int CK = C_ * K_;            // 896

typedef __attribute__((ext_vector_type(8))) _Float16 half8v;   // 4 VGPR MFMA frag
typedef __attribute__((ext_vector_type(4))) float f32x4;

__device__ __forceinline__ float fast_tanh(float v) {
    // tanh(v) = sign(v) * (1 - 2/(e^{2|v|}+1)); rcp is ~1e-5 accurate, fine here
    float a = fabsf(v);
    float e = __expf(2.0f * a);
    float t = fmaf(-2.0f, __builtin_amdgcn_rcpf(e + 1.0f), 1.0f);
    unsigned s = __float_as_uint(v) & 0x80000000u;
    return __uint_as_float(__float_as_uint(t) | s);
}

// one fused kernel: 256 l-rows x 16 d per block; 4 waves x 64 rows each.
// fp16 single-term MFMA (x,W ~ N(0,~1): fp16 RNE err 2^-11 -> out err ~1.6e-3,
// subdominant to the observed 0.0156). Replaces the bf16 hi/lo 3-term scheme:
// LDS 57->28.7KB (5 blocks/CU by LDS), A-frags halved, MFMA count /3.
// m-tiles in PAIRS (outer loop, unroll 1) -> live set ~100 VGPR; launch_bounds
// (256,2) deliberately invokes the empirical 128-VGPR cap (rounds 7/8) which
// now FITS -> 4 waves/SIMD, 16 waves/CU (2x round 9's ceiling).
__global__ __launch_bounds__(256, 2) void sidechain_fused(
        const float* __restrict__ x, const float* __restrict__ W,
        float* __restrict__ out) {
    __shared__ _Float16 Bs[7 * 16 * C_];   // [k][d_local][cin], XOR-swizzled 16B granules

    const int tid = threadIdx.x;
    const int b  = blockIdx.x >> 4;
    const int l0 = (blockIdx.x & 15) * 256;
    const int d0 = blockIdx.y * 16;

    const float* xb = x + (size_t)b * (L_ * C_);

    // ---- stage + convert W tile straight from fp32 global (RNE to fp16)
    {
        const int dl = tid >> 4;       // 0..15: d row
        const int g  = tid & 15;       // cin granule (8 cins)
        const int gp = g ^ dl;         // swizzled granule slot
        const float* wp = W + (size_t)(d0 + dl) * CK + g * 56;  // 8 cins x 7 k, contiguous
        float wbuf[56];
#pragma unroll
        for (int i = 0; i < 14; ++i)
            *reinterpret_cast<float4*>(&wbuf[i * 4]) =
                *reinterpret_cast<const float4*>(&wp[i * 4]);
#pragma unroll
        for (int k = 0; k < 7; ++k) {
            half8v h;
#pragma unroll
            for (int c = 0; c < 8; ++c) h[c] = (_Float16)wbuf[c * 7 + k];
            *reinterpret_cast<half8v*>(&Bs[(k * 16 + dl) * C_ + gp * 8]) = h;
        }
    }
    __syncthreads();

    const int wv   = tid >> 6;
    const int lane = tid & 63;
    const int rA   = lane & 15;    // A row / B col(d) / D col
    const int kg   = lane >> 4;    // 0..3
    const int dcol = d0 + rA;

#pragma unroll 1
    for (int half = 0; half < 2; ++half) {     // 2 m-tiles per iteration
        // ---- A fragments for this pair: load fp32, convert RNE fp16
        half8v A[2][4];
#pragma unroll
        for (int m = 0; m < 2; ++m) {
            int mt = half * 2 + m;
            int r = l0 + 6 + wv * 64 + mt * 16 + rA;
            if (r > L_ - 1) r = L_ - 1;        // clamped rows feed masked-out outputs only
            const float* xr = xb + (size_t)r * C_;
#pragma unroll
            for (int ks = 0; ks < 4; ++ks) {
                const float* p = xr + ks * 32 + kg * 8;
                const float4 f0 = *reinterpret_cast<const float4*>(p);
                const float4 f1 = *reinterpret_cast<const float4*>(p + 4);
                half8v h;
                h[0] = (_Float16)f0.x; h[1] = (_Float16)f0.y;
                h[2] = (_Float16)f0.z; h[3] = (_Float16)f0.w;
                h[4] = (_Float16)f1.x; h[5] = (_Float16)f1.y;
                h[6] = (_Float16)f1.z; h[7] = (_Float16)f1.w;
                A[m][ks] = h;
            }
        }

        // ---- epilogue x values for this pair: 10 rows cover r(0..3)+nt(0..6)
        float xv[2][10];
#pragma unroll
        for (int m = 0; m < 2; ++m) {
            int mt = half * 2 + m;
            int base = l0 + wv * 64 + mt * 16 + kg * 4;
#pragma unroll
            for (int r2 = 0; r2 < 10; ++r2) {
                int row = base + r2;
                if (row > L_ - 1) row = L_ - 1;    // OOB only for masked-out outputs
                xv[m][r2] = xb[(size_t)row * C_ + dcol];
            }
        }

        f32x4 oacc[2];
#pragma unroll
        for (int m = 0; m < 2; ++m) oacc[m] = (f32x4)(0.0f);

#pragma unroll
        for (int nt = 0; nt < 7; ++nt) {       // n-tile == tap k
            f32x4 acc[2];
#pragma unroll
            for (int m = 0; m < 2; ++m) acc[m] = (f32x4)(0.0f);
#pragma unroll
            for (int ks = 0; ks < 4; ++ks) {
                int gp2 = (ks * 4 + kg) ^ rA;
                const half8v Bf = *reinterpret_cast<const half8v*>(&Bs[(nt * 16 + rA) * C_ + gp2 * 8]);
#pragma unroll
                for (int m = 0; m < 2; ++m)
                    acc[m] = __builtin_amdgcn_mfma_f32_16x16x32_f16(A[m][ks], Bf, acc[m], 0, 0, 0);
            }
            // fused FIR epilogue for tap nt (register-resident x)
#pragma unroll
            for (int m = 0; m < 2; ++m)
#pragma unroll
                for (int r = 0; r < 4; ++r)
                    oacc[m][r] = fmaf(xv[m][r + nt], fast_tanh(acc[m][r]), oacc[m][r]);
        }

#pragma unroll
        for (int m = 0; m < 2; ++m) {
            int mt = half * 2 + m;
#pragma unroll
            for (int r = 0; r < 4; ++r) {
                int l = l0 + wv * 64 + mt * 16 + kg * 4 + r;
                if (l < LP) out[((size_t)b * LP + l) * C_ + dcol] = oacc[m][r];
            }
        }
    }
}

} // namespace

extern "C" void kernel_launch(void* const* d_in, const int* in_sizes, int n_in,
                              void* d_out, int out_size, void* d_ws, size_t ws_size,
                              hipStream_t stream) {
    const float* x = (const float*)d_in[0];
    const float* w = (const float*)d_in[1];
    float* out     = (float*)d_out;
    (void)d_ws; (void)ws_size; (void)in_sizes; (void)n_in; (void)out_size;

    dim3 grid(B_ * 16, C_ / 16);
    sidechain_fused<<<grid, dim3(256), 0, stream>>>(x, w, out);
}

// Round 12
// 87.946 us; speedup vs baseline: 2.7441x; 1.0333x over previous
//
#include <hip/hip_runtime.h>
#include <math.h>

namespace {

constexpr int B_ = 8, L_ = 4096, C_ = 128, K_ = 7;
constexpr int LP = L_ - K_ + 1;        // 4090
constexpr int CK = C_ * K_;            // 896

typedef __attribute__((ext_vector_type(8))) _Float16 half8v;   // 4 VGPR MFMA frag
typedef __attribute__((ext_vector_type(4))) float f32x4;

// tanh(v) = 1 - 2/(e^{2v}+1)  — valid for both signs, no abs/sign dance.
// v->+inf: e=inf, rcp=0, t=1.  v->-inf: e=0, t=-1.  rcp err ~1e-5, fine.
__device__ __forceinline__ float fast_tanh(float v) {
    float e = __expf(2.0f * v);
    return fmaf(-2.0f, __builtin_amdgcn_rcpf(e + 1.0f), 1.0f);
}

// One fused kernel: 256 l-rows x 16 d per block; 4 waves x 64 rows each.
// fp16 single-term MFMA (absmax 0.03125, passes). Round-11 structure was
// exposed-latency-bound (~36us vs ~5us issue floor): A/xv load windows and
// the single MFMA dep chain per nt sat on the critical path. This version:
//  - 4 m-tiles, software-pipelined depth 1 with NAMED double buffers
//    (static indexing only — dynamic-indexed arrays go to scratch)
//  - loads for tile i+1 issue before compute of tile i (waitcnt hidden
//    under ~1750cyc of MFMA+tanh)
//  - 2 independent MFMA accumulator chains per nt (ks even/odd) for ILP
// Live set ~90-110 VGPR -> fits the (256,2) 128-VGPR cap with no spill.
__global__ __launch_bounds__(256, 2) void sidechain_fused(
        const float* __restrict__ x, const float* __restrict__ W,
        float* __restrict__ out) {
    __shared__ _Float16 Bs[7 * 16 * C_];   // [k][d_local][cin], XOR-swizzled 16B granules

    const int tid = threadIdx.x;
    const int b  = blockIdx.x >> 4;
    const int l0 = (blockIdx.x & 15) * 256;
    const int d0 = blockIdx.y * 16;
    const float* xb = x + (size_t)b * (L_ * C_);

    // ---- stage + convert W tile straight from fp32 global (RNE to fp16)
    {
        const int dl = tid >> 4;       // 0..15: d row
        const int g  = tid & 15;       // cin granule (8 cins)
        const int gp = g ^ dl;         // swizzled granule slot
        const float* wp = W + (size_t)(d0 + dl) * CK + g * 56;  // 8 cins x 7 k, contiguous
        float wbuf[56];
#pragma unroll
        for (int i = 0; i < 14; ++i)
            *reinterpret_cast<float4*>(&wbuf[i * 4]) =
                *reinterpret_cast<const float4*>(&wp[i * 4]);
#pragma unroll
        for (int k = 0; k < 7; ++k) {
            half8v h;
#pragma unroll
            for (int c = 0; c < 8; ++c) h[c] = (_Float16)wbuf[c * 7 + k];
            *reinterpret_cast<half8v*>(&Bs[(k * 16 + dl) * C_ + gp * 8]) = h;
        }
    }
    __syncthreads();

    const int wv   = tid >> 6;
    const int lane = tid & 63;
    const int rA   = lane & 15;    // A row / B col(d) / D col
    const int kg   = lane >> 4;    // 0..3
    const int dcol = d0 + rA;
    const int rowA0 = l0 + 6 + wv * 64 + rA;   // + mt*16
    const int rowX0 = l0 + wv * 64 + kg * 4;   // + mt*16 + r2

    auto loadA = [&](int mt, half8v (&A)[4]) {
        int r = rowA0 + mt * 16;
        if (r > L_ - 1) r = L_ - 1;            // clamped rows feed masked-out outputs only
        const float* xr = xb + (size_t)r * C_;
#pragma unroll
        for (int ks = 0; ks < 4; ++ks) {
            const float* p = xr + ks * 32 + kg * 8;
            const float4 f0 = *reinterpret_cast<const float4*>(p);
            const float4 f1 = *reinterpret_cast<const float4*>(p + 4);
            half8v h;
            h[0] = (_Float16)f0.x; h[1] = (_Float16)f0.y;
            h[2] = (_Float16)f0.z; h[3] = (_Float16)f0.w;
            h[4] = (_Float16)f1.x; h[5] = (_Float16)f1.y;
            h[6] = (_Float16)f1.z; h[7] = (_Float16)f1.w;
            A[ks] = h;
        }
    };
    auto loadXV = [&](int mt, float (&xv)[10]) {
        int base = rowX0 + mt * 16;
#pragma unroll
        for (int r2 = 0; r2 < 10; ++r2) {
            int row = base + r2;
            if (row > L_ - 1) row = L_ - 1;    // OOB only for masked-out outputs
            xv[r2] = xb[(size_t)row * C_ + dcol];
        }
    };
    auto compute = [&](int mt, const half8v (&A)[4], const float (&xv)[10]) {
        f32x4 oacc = (f32x4)(0.0f);
#pragma unroll
        for (int nt = 0; nt < 7; ++nt) {       // n-tile == tap k
            f32x4 a0 = (f32x4)(0.0f), a1 = (f32x4)(0.0f);   // 2 indep chains
#pragma unroll
            for (int ks = 0; ks < 4; ks += 2) {
                int g0 = (ks * 4 + kg) ^ rA;
                int g1 = ((ks + 1) * 4 + kg) ^ rA;
                const half8v B0 = *reinterpret_cast<const half8v*>(&Bs[(nt * 16 + rA) * C_ + g0 * 8]);
                const half8v B1 = *reinterpret_cast<const half8v*>(&Bs[(nt * 16 + rA) * C_ + g1 * 8]);
                a0 = __builtin_amdgcn_mfma_f32_16x16x32_f16(A[ks],     B0, a0, 0, 0, 0);
                a1 = __builtin_amdgcn_mfma_f32_16x16x32_f16(A[ks + 1], B1, a1, 0, 0, 0);
            }
#pragma unroll
            for (int r = 0; r < 4; ++r)
                oacc[r] = fmaf(xv[r + nt], fast_tanh(a0[r] + a1[r]), oacc[r]);
        }
#pragma unroll
        for (int r = 0; r < 4; ++r) {
            int l = rowX0 + mt * 16 + r;
            if (l < LP) out[((size_t)b * LP + l) * C_ + dcol] = oacc[r];
        }
    };

    // software pipeline, depth 1, named buffers (all statically indexed)
    half8v A0[4], A1[4];
    float  xv0[10], xv1[10];
    loadA(0, A0); loadXV(0, xv0);
    loadA(1, A1); loadXV(1, xv1);
    compute(0, A0, xv0);
    loadA(2, A0); loadXV(2, xv0);      // in flight under compute(1)
    compute(1, A1, xv1);
    loadA(3, A1); loadXV(3, xv1);      // in flight under compute(2)
    compute(2, A0, xv0);
    compute(3, A1, xv1);
}

} // namespace

extern "C" void kernel_launch(void* const* d_in, const int* in_sizes, int n_in,
                              void* d_out, int out_size, void* d_ws, size_t ws_size,
                              hipStream_t stream) {
    const float* x = (const float*)d_in[0];
    const float* w = (const float*)d_in[1];
    float* out     = (float*)d_out;
    (void)d_ws; (void)ws_size; (void)in_sizes; (void)n_in; (void)out_size;

    dim3 grid(B_ * 16, C_ / 16);
    sidechain_fused<<<grid, dim3(256), 0, stream>>>(x, w, out);
}